// Round 14
// baseline (266.302 us; speedup 1.0000x reference)
//
#include <hip/hip_runtime.h>
#include <math.h>

#define S_DIM 490
#define NPATCH 49
#define EPSF 1e-8f
#define SP 512            // padded station dim
#define CI 8192           // injected columns: b(8)*w(64)*m(16)
#define CPB 32            // main columns per block
#define NBLK 256
#define HEAVY0 252        // blocks 252..255 also own 16 shared cols each
#define OMHALF (48 * 512) // shorts per om buffer
#define RINGOFF (2 * OMHALF)

typedef __attribute__((ext_vector_type(8))) short bf16x8;
typedef __attribute__((ext_vector_type(4))) float f32x4;

__device__ __forceinline__ unsigned short f2bf(float x) {
    unsigned int u = __float_as_uint(x);
    unsigned int r = (u + 0x7FFF + ((u >> 16) & 1)) >> 16;
    return (unsigned short)r;
}
__device__ __forceinline__ float bf2f(unsigned short u) {
    return __uint_as_float(((unsigned int)u) << 16);
}
__device__ __forceinline__ void gload16(const void* g, void* l) {
    __builtin_amdgcn_global_load_lds(
        (const __attribute__((address_space(1))) unsigned int*)g,
        (__attribute__((address_space(3))) unsigned int*)l, 16, 0, 0);
}

// ---------------- max |img|
__global__ void k_max(const float* __restrict__ img, float* __restrict__ encmax) {
    __shared__ float red[256];
    float m = 0.f;
    for (int i = threadIdx.x; i < 8 * 28 * 28; i += 256)
        m = fmaxf(m, fabsf(img[i]));
    red[threadIdx.x] = m;
    __syncthreads();
    for (int s = 128; s > 0; s >>= 1) {
        if (threadIdx.x < s) red[threadIdx.x] = fmaxf(red[threadIdx.x], red[threadIdx.x + s]);
        __syncthreads();
    }
    if (threadIdx.x == 0) *encmax = red[0];
}

// ---------------- K1[w][t] = ww[t][w]*softplus(gain[t]);  K2[t] = bias[t]
__global__ void k_prep(const float* __restrict__ ww, const float* __restrict__ sg,
                       const float* __restrict__ sb, float* __restrict__ K1,
                       float* __restrict__ K2) {
    int i = blockIdx.x * 256 + threadIdx.x;
    if (i < 64 * SP) {
        int w = i >> 9, t = i & (SP - 1);
        K1[i] = (t < S_DIM) ? ww[t * 64 + w] * log1pf(expf(sg[t])) : 0.f;
    }
    if (i < SP) K2[i] = (i < S_DIM) ? sb[i] : 0.f;
}

// ---------------- g0[t] = 0.25*relu(1e-4 * colsum_s conn[s][t])
__global__ void k_g0(const float* __restrict__ conn, float* __restrict__ g0) {
    int t = blockIdx.x;
    float s = 0.f;
    if (t < S_DIM)
        for (int ss = threadIdx.x; ss < S_DIM; ss += 256)
            s += conn[ss * S_DIM + t];
    __shared__ float red[256];
    red[threadIdx.x] = s;
    __syncthreads();
    for (int st = 128; st > 0; st >>= 1) {
        if (threadIdx.x < st) red[threadIdx.x] += red[threadIdx.x + st];
        __syncthreads();
    }
    if (threadIdx.x == 0) g0[t] = (t < S_DIM) ? 0.25f * fmaxf(1e-4f * red[0], 0.f) : 0.f;
}

// ---------------- packed conn for 32-row t-strips:
// connP[((strip*2+tt)*16+k)*512 + lane*8 + j] = conn[s][t]
__global__ void k_connP(const float* __restrict__ conn, unsigned short* __restrict__ connP) {
    int i = blockIdx.x * 256 + threadIdx.x;
    int j    = i & 7;
    int lane = (i >> 3) & 63;
    int k    = (i >> 9) & 15;
    int tt   = (i >> 13) & 1;
    int strip = i >> 14;
    int t = strip * 32 + tt * 16 + (lane & 15);
    int s = k * 32 + (lane >> 4) * 8 + j;
    float v = (t < S_DIM && s < S_DIM) ? conn[s * S_DIM + t] : 0.f;
    connP[i] = f2bf(v);
}

// ---------------- injT [8192 c][64 t] f32
__global__ void k_inj(const float* __restrict__ img, const float* __restrict__ encmax,
                      float* __restrict__ injT) {
    int i = blockIdx.x * 256 + threadIdx.x;
    int c = i >> 6, tt = i & 63;
    int b = c >> 10, w = (c >> 4) & 63, m = c & 15;
    float em = *encmax;
    float scale = (em > EPSF) ? (0.3f / em) : 0.3f;
    float v = 0.f;
    if (tt < NPATCH) {
        int r = (tt / 7) * 4 + (m >> 2);
        int col = (tt % 7) * 4 + (m & 3);
        float wgt = 1.0f - fabsf((float)w - 32.0f) * (1.0f / 64.0f);
        v = img[(b * 28 + r) * 28 + col] * wgt * scale;
    }
    injT[i] = v;
}

#define MFMA(A, B, C) __builtin_amdgcn_mfma_f32_16x16x32_bf16(A, B, C, 0, 0, 0)

// ---------------- persistent block-local recurrence.
// conn a-slices stream L2 -> per-wave 2-slot LDS ring via global_load_lds
// (counted vmcnt(2), never drained in-loop); om double-buffered, XOR-swizzled.
__global__ __launch_bounds__(1024, 4) void k_run(
    const unsigned short* __restrict__ connP, const float* __restrict__ injT,
    const float* __restrict__ K1, const float* __restrict__ K2,
    const float* __restrict__ g0, const int* __restrict__ injSteps,
    float* __restrict__ partials, float* __restrict__ partialsS)
{
    __shared__ unsigned short LDSA[RINGOFF + 16 * 2 * 2 * 512];   // 160 KB exactly
    const int bk   = blockIdx.x;
    const int tid  = threadIdx.x;
    const int wv   = tid >> 6;                // t-strip 0..15 (32 t each)
    const int lane = tid & 63;
    const int l16  = lane & 15, lq = lane >> 4;
    const bool heavy = (bk >= HEAVY0);
    const int c0 = bk * CPB;

    const int nInj = injSteps[0];

    // ring slot LDS pointers (wave-uniform) + global conn bases (per-lane)
    unsigned short* rs00 = &LDSA[RINGOFF + ((wv * 2 + 0) * 2 + 0) * 512];
    unsigned short* rs01 = &LDSA[RINGOFF + ((wv * 2 + 0) * 2 + 1) * 512];
    unsigned short* rs10 = &LDSA[RINGOFF + ((wv * 2 + 1) * 2 + 0) * 512];
    unsigned short* rs11 = &LDSA[RINGOFF + ((wv * 2 + 1) * 2 + 1) * 512];
    const unsigned short* gA0 = connP + (size_t)(wv * 32) * 512 + lane * 8;
    const unsigned short* gA1 = gA0 + 16 * 512;

    // hoisted per-step constants
    f32x4 k1r[2][2], k2r[2], k1h[2];
    #pragma unroll
    for (int tt = 0; tt < 2; ++tt) {
        int t0 = (wv << 5) + tt * 16 + lq * 4;
        k2r[tt] = *(const f32x4*)(K2 + t0);
        #pragma unroll
        for (int cc = 0; cc < 2; ++cc) {
            int w = (2 * bk + cc) & 63;
            k1r[tt][cc] = *(const f32x4*)(K1 + w * SP + t0);
        }
        if (heavy) {
            int wsh = (bk - HEAVY0) * 16 + l16;
            k1h[tt] = *(const f32x4*)(K1 + wsh * SP + t0);
        }
    }

    // om XOR-swizzle read bases (rows l16, 16+l16, 32+l16 share the same mask)
    const int msk = (l16 & 7) << 3;
    const int lo  = (lq * 8) ^ (msk & 24);
    const int s5  = msk & 32;
    const int be0 = l16 * 512 + lo + s5;
    const int bo0 = l16 * 512 + lo + (32 ^ s5);
    const int be1 = be0 + 16 * 512, bo1 = bo0 + 16 * 512;
    const int be2 = be0 + 32 * 512, bo2 = bo0 + 32 * 512;

    f32x4 fld[2][2] = {};
    f32x4 fld2[2] = {};
    unsigned short* om1 = LDSA + OMHALF;

    // ---- analytic step 0: fm = |gate*inj|*0.85 + g0[t]; om -> om[1]
    {
        const bool inj0 = (wv < 2) && (0 < nInj);
        #pragma unroll
        for (int tt = 0; tt < 2; ++tt) {
            int t0 = (wv << 5) + tt * 16 + lq * 4;
            f32x4 g0v = *(const f32x4*)(g0 + t0);
            f32x4 k2 = k2r[tt];
            #pragma unroll
            for (int cc = 0; cc < 2; ++cc) {
                int cg = c0 + cc * 16 + l16;
                f32x4 k1 = k1r[tt][cc];
                f32x4 f = {};
                if (inj0) f = *(const f32x4*)(injT + (size_t)cg * 64 + t0);
                float o_[4];
                #pragma unroll
                for (int r = 0; r < 4; ++r) {
                    float fm = fabsf(f[r]) * 0.85f + g0v[r];
                    float x  = fabsf(fm * k1[r] + k2[r]);
                    float e  = exp2f(x * 2.8853900817779268f);
                    o_[r] = 1.f - 2.f * __builtin_amdgcn_rcpf(e + 1.f);
                    f[r] = fm;
                }
                fld[tt][cc] = f;
                unsigned int r01, r23;
                asm("v_cvt_pk_bf16_f32 %0, %1, %2" : "=v"(r01) : "v"(o_[0]), "v"(o_[1]));
                asm("v_cvt_pk_bf16_f32 %0, %1, %2" : "=v"(r23) : "v"(o_[2]), "v"(o_[3]));
                int cl = cc * 16 + l16;
                *(uint2*)&om1[(cl * 512 + t0) ^ ((cl & 7) << 3)] = make_uint2(r01, r23);
            }
            if (heavy) {
                f32x4 k1 = k1h[tt];
                float oh[4];
                f32x4 fh;
                #pragma unroll
                for (int r = 0; r < 4; ++r) {
                    float fm = g0v[r];
                    float x  = fabsf(fm * k1[r] + k2[r]);
                    float e  = exp2f(x * 2.8853900817779268f);
                    oh[r] = 1.f - 2.f * __builtin_amdgcn_rcpf(e + 1.f);
                    fh[r] = fm;
                }
                fld2[tt] = fh;
                unsigned int h01, h23;
                asm("v_cvt_pk_bf16_f32 %0, %1, %2" : "=v"(h01) : "v"(oh[0]), "v"(oh[1]));
                asm("v_cvt_pk_bf16_f32 %0, %1, %2" : "=v"(h23) : "v"(oh[2]), "v"(oh[3]));
                int cl = 32 + l16;
                *(uint2*)&om1[(cl * 512 + t0) ^ ((cl & 7) << 3)] = make_uint2(h01, h23);
            }
        }
    }
    // prime the ring with slices k=0 (slot0) and k=1 (slot1)
    gload16(gA0, rs00);
    gload16(gA1, rs01);
    gload16(gA0 + 512, rs10);
    gload16(gA1 + 512, rs11);
    __syncthreads();   // drains vmcnt -> primed slices landed

    for (int st = 1; st < 15; ++st) {
        const unsigned short* bufR = LDSA + (st & 1) * OMHALF;
        unsigned short* bufW = LDSA + ((st + 1) & 1) * OMHALF;
        f32x4 acc[2][2] = {};
        f32x4 acc2[2] = {};
        // preload b(k=0)
        bf16x8 b0c = *(const bf16x8*)&bufR[be0];
        bf16x8 b1c = *(const bf16x8*)&bufR[be1];
        __builtin_amdgcn_s_setprio(1);
        #pragma unroll
        for (int k = 0; k < 16; ++k) {
            asm volatile("s_waitcnt vmcnt(2)" ::: "memory");   // slot[k&1] data ready
            const unsigned short* r0 = (k & 1) ? rs10 : rs00;
            const unsigned short* r1 = (k & 1) ? rs11 : rs01;
            bf16x8 a0 = *(const bf16x8*)(r0 + lane * 8);
            bf16x8 a1 = *(const bf16x8*)(r1 + lane * 8);
            bf16x8 b0n = b0c, b1n = b1c;
            if (k < 15) {      // prefetch b(k+1): odd k+1 -> bo + k*32, even -> be + (k+1)*32
                int off0 = ((k + 1) & 1) ? (bo0 + k * 32) : (be0 + (k + 1) * 32);
                int off1 = ((k + 1) & 1) ? (bo1 + k * 32) : (be1 + (k + 1) * 32);
                b0n = *(const bf16x8*)&bufR[off0];
                b1n = *(const bf16x8*)&bufR[off1];
            }
            acc[0][0] = MFMA(a0, b0c, acc[0][0]);
            acc[0][1] = MFMA(a0, b1c, acc[0][1]);
            acc[1][0] = MFMA(a1, b0c, acc[1][0]);
            acc[1][1] = MFMA(a1, b1c, acc[1][1]);
            if (heavy) {
                int offh = (k & 1) ? (bo2 + (k - 1) * 32) : (be2 + k * 32);
                bf16x8 b2 = *(const bf16x8*)&bufR[offh];
                acc2[0] = MFMA(a0, b2, acc2[0]);
                acc2[1] = MFMA(a1, b2, acc2[1]);
            }
            __builtin_amdgcn_sched_barrier(0);   // pin refill after MFMA (WAR on slot)
            {
                int kn = (k + 2) & 15;           // wraps to next step (conn invariant)
                gload16(gA0 + (size_t)kn * 512, (k & 1) ? rs10 : rs00);
                gload16(gA1 + (size_t)kn * 512, (k & 1) ? rs11 : rs01);
            }
            b0c = b0n; b1c = b1n;
        }
        __builtin_amdgcn_s_setprio(0);
        // no mid-step barrier: reads from bufR, writes to bufW

        const bool injNow = (wv < 2) && (st < nInj);
        #pragma unroll
        for (int tt = 0; tt < 2; ++tt) {
            int t0 = (wv << 5) + tt * 16 + lq * 4;
            f32x4 k2 = k2r[tt];
            #pragma unroll
            for (int cc = 0; cc < 2; ++cc) {
                int cg = c0 + cc * 16 + l16;
                f32x4 k1 = k1r[tt][cc];
                f32x4 f = fld[tt][cc];
                if (injNow) f += *(const f32x4*)(injT + (size_t)cg * 64 + t0);
                f32x4 ac = acc[tt][cc];
                float o_[4];
                #pragma unroll
                for (int r = 0; r < 4; ++r) {
                    float g  = fmaxf(ac[r], 0.f);
                    float fm = fabsf(f[r]) * 0.85f + 0.25f * g;
                    float x  = fabsf(fm * k1[r] + k2[r]);
                    float e  = exp2f(x * 2.8853900817779268f);
                    o_[r] = 1.f - 2.f * __builtin_amdgcn_rcpf(e + 1.f);
                    f[r] = fm;
                }
                fld[tt][cc] = f;
                unsigned int r01, r23;
                asm("v_cvt_pk_bf16_f32 %0, %1, %2" : "=v"(r01) : "v"(o_[0]), "v"(o_[1]));
                asm("v_cvt_pk_bf16_f32 %0, %1, %2" : "=v"(r23) : "v"(o_[2]), "v"(o_[3]));
                int cl = cc * 16 + l16;
                *(uint2*)&bufW[(cl * 512 + t0) ^ ((cl & 7) << 3)] = make_uint2(r01, r23);
            }
            if (heavy) {
                f32x4 k1 = k1h[tt];
                f32x4 fh = fld2[tt];
                f32x4 ah = acc2[tt];
                float oh[4];
                #pragma unroll
                for (int r = 0; r < 4; ++r) {
                    float g  = fmaxf(ah[r], 0.f);
                    float fm = fabsf(fh[r]) * 0.85f + 0.25f * g;
                    float x  = fabsf(fm * k1[r] + k2[r]);
                    float e  = exp2f(x * 2.8853900817779268f);
                    oh[r] = 1.f - 2.f * __builtin_amdgcn_rcpf(e + 1.f);
                    fh[r] = fm;
                }
                fld2[tt] = fh;
                unsigned int h01, h23;
                asm("v_cvt_pk_bf16_f32 %0, %1, %2" : "=v"(h01) : "v"(oh[0]), "v"(oh[1]));
                asm("v_cvt_pk_bf16_f32 %0, %1, %2" : "=v"(h23) : "v"(oh[2]), "v"(oh[3]));
                int cl = 32 + l16;
                *(uint2*)&bufW[(cl * 512 + t0) ^ ((cl & 7) << 3)] = make_uint2(h01, h23);
            }
        }
        __syncthreads();   // single barrier per step (drains wrap refills too)
    }

    // ---- per-block energy partials over stations 480..489 (final buf = om[1])
    if (wv == 0) {
        int cl = (lane < 48) ? lane : 0;
        #pragma unroll
        for (int o = 0; o < 10; ++o) {
            float v = bf2f(om1[(cl * 512 + 480 + o) ^ ((cl & 7) << 3)]);
            float e = v * v;
            float em = (lane < 32) ? e : 0.f;
            em += __shfl_xor(em, 1);  em += __shfl_xor(em, 2);
            em += __shfl_xor(em, 4);  em += __shfl_xor(em, 8);
            em += __shfl_xor(em, 16);
            if (lane == 0) partials[bk * 10 + o] = em;
            if (heavy) {
                float es = (lane >= 32 && lane < 48) ? e : 0.f;
                es += __shfl_xor(es, 1); es += __shfl_xor(es, 2);
                es += __shfl_xor(es, 4); es += __shfl_xor(es, 8);
                if (lane == 32) partialsS[(bk - HEAVY0) * 10 + o] = es;
            }
        }
    }
}

// ---------------- reduce partials -> features -> logits
__global__ void k_fin(const float* __restrict__ partials, const float* __restrict__ partialsS,
                      const float* __restrict__ rw, const float* __restrict__ rb,
                      float* __restrict__ out) {
    __shared__ float fe[80];
    int tid = threadIdx.x;
    if (tid < 80) {
        int b = tid / 10, o = tid % 10;
        float e = 0.f;
        #pragma unroll 8
        for (int j = 0; j < 32; ++j) e += partials[(b * 32 + j) * 10 + o];
        float es = 0.f;
        #pragma unroll
        for (int j = 0; j < 4; ++j) es += partialsS[j * 10 + o];
        e += 16.f * es + 2048.f * EPSF;
        fe[tid] = log1pf(e + EPSF);
    }
    __syncthreads();
    if (tid < 80) {
        int b = tid / 10, cls = tid % 10;
        float a = rb[cls];
        #pragma unroll
        for (int k = 0; k < 10; ++k) a += fe[b * 10 + k] * rw[cls * 10 + k];
        out[tid] = a;
    }
}

extern "C" void kernel_launch(void* const* d_in, const int* in_sizes, int n_in,
                              void* d_out, int out_size, void* d_ws, size_t ws_size,
                              hipStream_t stream) {
    (void)in_sizes; (void)n_in; (void)out_size; (void)ws_size;
    const float* img   = (const float*)d_in[0];
    const float* conn  = (const float*)d_in[1];
    const float* ww    = (const float*)d_in[2];
    const float* sgain = (const float*)d_in[3];
    const float* sbias = (const float*)d_in[4];
    const float* rw    = (const float*)d_in[5];
    const float* rb    = (const float*)d_in[6];
    const int* injsteps = (const int*)d_in[8];

    char* w = (char*)d_ws;
    unsigned short* connP = (unsigned short*)w;                 // 512 KB
    float* injT = (float*)(w + (size_t)SP * SP * 2);            // 2 MB
    float* K1   = injT + (size_t)CI * 64;                       // 128 KB
    float* K2   = K1 + 64 * SP;                                 // 2 KB
    float* g0   = K2 + SP;                                      // 2 KB
    float* encmax    = g0 + SP;
    float* partials  = encmax + 4;                              // 256*10
    float* partialsS = partials + NBLK * 10;                    // 4*10

    k_max  <<<1, 256, 0, stream>>>(img, encmax);
    k_prep <<<128, 256, 0, stream>>>(ww, sgain, sbias, K1, K2);
    k_g0   <<<SP, 256, 0, stream>>>(conn, g0);
    k_connP<<<(SP * SP) / 256, 256, 0, stream>>>(conn, connP);
    k_inj  <<<(CI * 64) / 256, 256, 0, stream>>>(img, encmax, injT);

    k_run<<<NBLK, 1024, 0, stream>>>(connP, injT, K1, K2, g0, injsteps, partials, partialsS);
    k_fin<<<1, 128, 0, stream>>>(partials, partialsS, rw, rb, (float*)d_out);
}

// Round 15
// 127.589 us; speedup vs baseline: 2.0872x; 2.0872x over previous
//
#include <hip/hip_runtime.h>
#include <math.h>

#define S_DIM 490
#define NPATCH 49
#define EPSF 1e-8f
#define SP 512            // padded station dim
#define CI 8192           // injected columns: b(8)*w(64)*m(16)
#define CPB 32            // main columns per block
#define NBLK 256
#define HEAVY0 252        // blocks 252..255 also own 16 shared cols each
#define OMS 520           // om LDS row stride (shorts)

typedef __attribute__((ext_vector_type(8))) short bf16x8;
typedef __attribute__((ext_vector_type(4))) float f32x4;

__device__ __forceinline__ unsigned short f2bf(float x) {
    unsigned int u = __float_as_uint(x);
    unsigned int r = (u + 0x7FFF + ((u >> 16) & 1)) >> 16;
    return (unsigned short)r;
}
__device__ __forceinline__ float bf2f(unsigned short u) {
    return __uint_as_float(((unsigned int)u) << 16);
}

// ---------------- max |img|
__global__ void k_max(const float* __restrict__ img, float* __restrict__ encmax) {
    __shared__ float red[256];
    float m = 0.f;
    for (int i = threadIdx.x; i < 8 * 28 * 28; i += 256)
        m = fmaxf(m, fabsf(img[i]));
    red[threadIdx.x] = m;
    __syncthreads();
    for (int s = 128; s > 0; s >>= 1) {
        if (threadIdx.x < s) red[threadIdx.x] = fmaxf(red[threadIdx.x], red[threadIdx.x + s]);
        __syncthreads();
    }
    if (threadIdx.x == 0) *encmax = red[0];
}

// ---------------- K1[w][t] = ww[t][w]*softplus(gain[t]);  K2[t] = bias[t]
__global__ void k_prep(const float* __restrict__ ww, const float* __restrict__ sg,
                       const float* __restrict__ sb, float* __restrict__ K1,
                       float* __restrict__ K2) {
    int i = blockIdx.x * 256 + threadIdx.x;
    if (i < 64 * SP) {
        int w = i >> 9, t = i & (SP - 1);
        K1[i] = (t < S_DIM) ? ww[t * 64 + w] * log1pf(expf(sg[t])) : 0.f;
    }
    if (i < SP) K2[i] = (i < S_DIM) ? sb[i] : 0.f;
}

// ---------------- g0[t] = 0.25*relu(1e-4 * colsum_s conn[s][t])  (exact step-0 gather)
// one block per t, 256-thread strided partial + tree reduce
__global__ void k_g0(const float* __restrict__ conn, float* __restrict__ g0) {
    int t = blockIdx.x;                         // 0..511
    float s = 0.f;
    if (t < S_DIM)
        for (int ss = threadIdx.x; ss < S_DIM; ss += 256)
            s += conn[ss * S_DIM + t];
    __shared__ float red[256];
    red[threadIdx.x] = s;
    __syncthreads();
    for (int st = 128; st > 0; st >>= 1) {
        if (threadIdx.x < st) red[threadIdx.x] += red[threadIdx.x + st];
        __syncthreads();
    }
    if (threadIdx.x == 0) g0[t] = (t < S_DIM) ? 0.25f * fmaxf(1e-4f * red[0], 0.f) : 0.f;
}

// ---------------- packed conn for 32-row t-strips:
// connP[((strip*2+tt)*16+k)*512 + lane*8 + j] = conn[s][t],
// t = strip*32 + tt*16 + (lane&15), s = k*32 + (lane>>4)*8 + j.
__global__ void k_connP(const float* __restrict__ conn, unsigned short* __restrict__ connP) {
    int i = blockIdx.x * 256 + threadIdx.x;     // 0 .. 512*512-1
    int j    = i & 7;
    int lane = (i >> 3) & 63;
    int k    = (i >> 9) & 15;
    int tt   = (i >> 13) & 1;
    int strip = i >> 14;
    int t = strip * 32 + tt * 16 + (lane & 15);
    int s = k * 32 + (lane >> 4) * 8 + j;
    float v = (t < S_DIM && s < S_DIM) ? conn[s * S_DIM + t] : 0.f;
    connP[i] = f2bf(v);
}

// ---------------- injT [8192 c][64 t] f32  (c = b*1024 + w*16 + m)
__global__ void k_inj(const float* __restrict__ img, const float* __restrict__ encmax,
                      float* __restrict__ injT) {
    int i = blockIdx.x * 256 + threadIdx.x;     // c*64 + tt
    int c = i >> 6, tt = i & 63;
    int b = c >> 10, w = (c >> 4) & 63, m = c & 15;
    float em = *encmax;
    float scale = (em > EPSF) ? (0.3f / em) : 0.3f;
    float v = 0.f;
    if (tt < NPATCH) {
        int r = (tt / 7) * 4 + (m >> 2);
        int col = (tt % 7) * 4 + (m & 3);
        float wgt = 1.0f - fabsf((float)w - 32.0f) * (1.0f / 64.0f);
        v = img[(b * 28 + r) * 28 + col] * wgt * scale;
    }
    injT[i] = v;
}

#define MFMA(A, B, C) __builtin_amdgcn_mfma_f32_16x16x32_bf16(A, B, C, 0, 0, 0)

// ---------------- persistent block-local recurrence: 32(+16) cols/block,
// om double-buffered in LDS (1 barrier/step). Step 0 is analytic (no MFMA).
__global__ __launch_bounds__(1024, 4) void k_run(
    const unsigned short* __restrict__ connP, const float* __restrict__ injT,
    const float* __restrict__ K1, const float* __restrict__ K2,
    const float* __restrict__ g0, const int* __restrict__ injSteps,
    float* __restrict__ partials, float* __restrict__ partialsS)
{
    __shared__ unsigned short om[2][48 * OMS];   // ~99.8 KB
    const int bk   = blockIdx.x;
    const int tid  = threadIdx.x;
    const int wv   = tid >> 6;                // t-strip 0..15 (32 t each)
    const int lane = tid & 63;
    const int l16  = lane & 15, lq = lane >> 4;
    const bool heavy = (bk >= HEAVY0);
    const int c0 = bk * CPB;

    const int nInj = injSteps[0];
    const unsigned short* aP = connP + (size_t)(wv * 32) * 512 + lane * 8;

    // hoisted per-step constants (valid across all steps)
    f32x4 k1r[2][2], k2r[2], k1h[2];
    #pragma unroll
    for (int tt = 0; tt < 2; ++tt) {
        int t0 = (wv << 5) + tt * 16 + lq * 4;
        k2r[tt] = *(const f32x4*)(K2 + t0);
        #pragma unroll
        for (int cc = 0; cc < 2; ++cc) {
            int w = (2 * bk + cc) & 63;            // (cg>>4)&63, wave-uniform
            k1r[tt][cc] = *(const f32x4*)(K1 + w * SP + t0);
        }
        if (heavy) {
            int wsh = (bk - HEAVY0) * 16 + l16;    // shared-col w index (per-lane)
            k1h[tt] = *(const f32x4*)(K1 + wsh * SP + t0);
        }
    }

    // LDS read bases for b-fragments
    const int rb0 = l16 * OMS;
    const int rb1 = (16 + l16) * OMS;
    const int rb2 = (32 + l16) * OMS;

    f32x4 fld[2][2] = {};
    f32x4 fld2[2] = {};

    // ---- analytic step 0: field = gate*inj; fm = |field|*0.85 + g0[t];
    // om(step1 input) = |tanh(fm*k1+k2)|  -> write om[1] (bufR of st=1)
    {
        const bool inj0 = (wv < 2) && (0 < nInj);
        #pragma unroll
        for (int tt = 0; tt < 2; ++tt) {
            int t0 = (wv << 5) + tt * 16 + lq * 4;
            f32x4 g0v = *(const f32x4*)(g0 + t0);
            f32x4 k2 = k2r[tt];
            #pragma unroll
            for (int cc = 0; cc < 2; ++cc) {
                int cg = c0 + cc * 16 + l16;
                f32x4 k1 = k1r[tt][cc];
                f32x4 f = {};
                if (inj0) f = *(const f32x4*)(injT + (size_t)cg * 64 + t0);
                float o_[4];
                #pragma unroll
                for (int r = 0; r < 4; ++r) {
                    float fm = fabsf(f[r]) * 0.85f + g0v[r];
                    float x  = fabsf(fm * k1[r] + k2[r]);
                    float e  = exp2f(x * 2.8853900817779268f);
                    o_[r] = 1.f - 2.f * __builtin_amdgcn_rcpf(e + 1.f);
                    f[r] = fm;
                }
                fld[tt][cc] = f;
                unsigned int r01, r23;
                asm("v_cvt_pk_bf16_f32 %0, %1, %2" : "=v"(r01) : "v"(o_[0]), "v"(o_[1]));
                asm("v_cvt_pk_bf16_f32 %0, %1, %2" : "=v"(r23) : "v"(o_[2]), "v"(o_[3]));
                int cl = cc * 16 + l16;
                *(uint2*)&om[1][cl * OMS + t0] = make_uint2(r01, r23);
            }
            if (heavy) {
                f32x4 k1 = k1h[tt];
                float oh[4];
                f32x4 fh;
                #pragma unroll
                for (int r = 0; r < 4; ++r) {
                    float fm = g0v[r];                       // field=0, no inj
                    float x  = fabsf(fm * k1[r] + k2[r]);
                    float e  = exp2f(x * 2.8853900817779268f);
                    oh[r] = 1.f - 2.f * __builtin_amdgcn_rcpf(e + 1.f);
                    fh[r] = fm;
                }
                fld2[tt] = fh;
                unsigned int h01, h23;
                asm("v_cvt_pk_bf16_f32 %0, %1, %2" : "=v"(h01) : "v"(oh[0]), "v"(oh[1]));
                asm("v_cvt_pk_bf16_f32 %0, %1, %2" : "=v"(h23) : "v"(oh[2]), "v"(oh[3]));
                *(uint2*)&om[1][(32 + l16) * OMS + t0] = make_uint2(h01, h23);
            }
        }
    }
    __syncthreads();

    for (int st = 1; st < 15; ++st) {
        const unsigned short* bufR = om[st & 1];
        unsigned short* bufW = om[(st + 1) & 1];
        f32x4 acc[2][2] = {};
        f32x4 acc2[2] = {};
        __builtin_amdgcn_s_setprio(1);
        #pragma unroll 4
        for (int k = 0; k < 16; ++k) {
            bf16x8 a0 = *(const bf16x8*)(aP + (size_t)(k)      * 512);
            bf16x8 a1 = *(const bf16x8*)(aP + (size_t)(16 + k) * 512);
            int sOff = k * 32 + lq * 8;
            bf16x8 b0 = *(const bf16x8*)&bufR[rb0 + sOff];
            bf16x8 b1 = *(const bf16x8*)&bufR[rb1 + sOff];
            acc[0][0] = MFMA(a0, b0, acc[0][0]);
            acc[0][1] = MFMA(a0, b1, acc[0][1]);
            acc[1][0] = MFMA(a1, b0, acc[1][0]);
            acc[1][1] = MFMA(a1, b1, acc[1][1]);
            if (heavy) {
                bf16x8 b2 = *(const bf16x8*)&bufR[rb2 + sOff];
                acc2[0] = MFMA(a0, b2, acc2[0]);
                acc2[1] = MFMA(a1, b2, acc2[1]);
            }
        }
        __builtin_amdgcn_s_setprio(0);
        // no mid-step barrier: reads were from bufR, writes go to bufW

        const bool injNow = (wv < 2) && (st < nInj);   // patches live at t<49
        #pragma unroll
        for (int tt = 0; tt < 2; ++tt) {
            int t0 = (wv << 5) + tt * 16 + lq * 4;
            f32x4 k2 = k2r[tt];
            #pragma unroll
            for (int cc = 0; cc < 2; ++cc) {
                int cg = c0 + cc * 16 + l16;
                f32x4 k1 = k1r[tt][cc];
                f32x4 f = fld[tt][cc];
                if (injNow) f += *(const f32x4*)(injT + (size_t)cg * 64 + t0);
                f32x4 ac = acc[tt][cc];
                float o_[4];
                #pragma unroll
                for (int r = 0; r < 4; ++r) {
                    float g  = fmaxf(ac[r], 0.f);
                    float fm = fabsf(f[r]) * 0.85f + 0.25f * g;   // sqrt(f^2+eps)~|f|
                    float x  = fabsf(fm * k1[r] + k2[r]);         // |tanh(x)|=tanh(|x|)
                    float e  = exp2f(x * 2.8853900817779268f);    // exp(2|x|), inf-safe
                    o_[r] = 1.f - 2.f * __builtin_amdgcn_rcpf(e + 1.f);
                    f[r] = fm;
                }
                fld[tt][cc] = f;
                unsigned int r01, r23;
                asm("v_cvt_pk_bf16_f32 %0, %1, %2" : "=v"(r01) : "v"(o_[0]), "v"(o_[1]));
                asm("v_cvt_pk_bf16_f32 %0, %1, %2" : "=v"(r23) : "v"(o_[2]), "v"(o_[3]));
                int cl = cc * 16 + l16;
                *(uint2*)&bufW[cl * OMS + t0] = make_uint2(r01, r23);
            }
            if (heavy) {
                f32x4 k1 = k1h[tt];
                f32x4 fh = fld2[tt];
                f32x4 ah = acc2[tt];
                float oh[4];
                #pragma unroll
                for (int r = 0; r < 4; ++r) {
                    float g  = fmaxf(ah[r], 0.f);
                    float fm = fabsf(fh[r]) * 0.85f + 0.25f * g;
                    float x  = fabsf(fm * k1[r] + k2[r]);
                    float e  = exp2f(x * 2.8853900817779268f);
                    oh[r] = 1.f - 2.f * __builtin_amdgcn_rcpf(e + 1.f);
                    fh[r] = fm;
                }
                fld2[tt] = fh;
                unsigned int h01, h23;
                asm("v_cvt_pk_bf16_f32 %0, %1, %2" : "=v"(h01) : "v"(oh[0]), "v"(oh[1]));
                asm("v_cvt_pk_bf16_f32 %0, %1, %2" : "=v"(h23) : "v"(oh[2]), "v"(oh[3]));
                *(uint2*)&bufW[(32 + l16) * OMS + t0] = make_uint2(h01, h23);
            }
        }
        __syncthreads();   // single barrier per step
    }

    // ---- per-block energy partials over stations 480..489 (final buf = om[1])
    if (wv == 0) {
        int cl = (lane < 48) ? lane : 0;
        #pragma unroll
        for (int o = 0; o < 10; ++o) {
            float v = bf2f(om[1][cl * OMS + 480 + o]);
            float e = v * v;
            float em = (lane < 32) ? e : 0.f;
            em += __shfl_xor(em, 1);  em += __shfl_xor(em, 2);
            em += __shfl_xor(em, 4);  em += __shfl_xor(em, 8);
            em += __shfl_xor(em, 16);
            if (lane == 0) partials[bk * 10 + o] = em;
            if (heavy) {
                float es = (lane >= 32 && lane < 48) ? e : 0.f;
                es += __shfl_xor(es, 1); es += __shfl_xor(es, 2);
                es += __shfl_xor(es, 4); es += __shfl_xor(es, 8);
                if (lane == 32) partialsS[(bk - HEAVY0) * 10 + o] = es;
            }
        }
    }
}

// ---------------- reduce partials -> features -> logits
__global__ void k_fin(const float* __restrict__ partials, const float* __restrict__ partialsS,
                      const float* __restrict__ rw, const float* __restrict__ rb,
                      float* __restrict__ out) {
    __shared__ float fe[80];
    int tid = threadIdx.x;
    if (tid < 80) {
        int b = tid / 10, o = tid % 10;
        float e = 0.f;
        #pragma unroll 8
        for (int j = 0; j < 32; ++j) e += partials[(b * 32 + j) * 10 + o];
        float es = 0.f;
        #pragma unroll
        for (int j = 0; j < 4; ++j) es += partialsS[j * 10 + o];
        e += 16.f * es + 2048.f * EPSF;      // shared cols x16 copies; restore +eps/elem
        fe[tid] = log1pf(e + EPSF);
    }
    __syncthreads();
    if (tid < 80) {
        int b = tid / 10, cls = tid % 10;
        float a = rb[cls];
        #pragma unroll
        for (int k = 0; k < 10; ++k) a += fe[b * 10 + k] * rw[cls * 10 + k];
        out[tid] = a;
    }
}

extern "C" void kernel_launch(void* const* d_in, const int* in_sizes, int n_in,
                              void* d_out, int out_size, void* d_ws, size_t ws_size,
                              hipStream_t stream) {
    (void)in_sizes; (void)n_in; (void)out_size; (void)ws_size;
    const float* img   = (const float*)d_in[0];
    const float* conn  = (const float*)d_in[1];
    const float* ww    = (const float*)d_in[2];
    const float* sgain = (const float*)d_in[3];
    const float* sbias = (const float*)d_in[4];
    const float* rw    = (const float*)d_in[5];
    const float* rb    = (const float*)d_in[6];
    const int* injsteps = (const int*)d_in[8];

    char* w = (char*)d_ws;
    unsigned short* connP = (unsigned short*)w;                 // 512 KB
    float* injT = (float*)(w + (size_t)SP * SP * 2);            // 2 MB
    float* K1   = injT + (size_t)CI * 64;                       // 128 KB
    float* K2   = K1 + 64 * SP;                                 // 2 KB
    float* g0   = K2 + SP;                                      // 2 KB
    float* encmax    = g0 + SP;
    float* partials  = encmax + 4;                              // 256*10
    float* partialsS = partials + NBLK * 10;                    // 4*10

    k_max  <<<1, 256, 0, stream>>>(img, encmax);
    k_prep <<<128, 256, 0, stream>>>(ww, sgain, sbias, K1, K2);
    k_g0   <<<SP, 256, 0, stream>>>(conn, g0);
    k_connP<<<(SP * SP) / 256, 256, 0, stream>>>(conn, connP);
    k_inj  <<<(CI * 64) / 256, 256, 0, stream>>>(img, encmax, injT);

    k_run<<<NBLK, 1024, 0, stream>>>(connP, injT, K1, K2, g0, injsteps, partials, partialsS);
    k_fin<<<1, 128, 0, stream>>>(partials, partialsS, rw, rb, (float*)d_out);
}